// Round 10
// baseline (15000.726 us; speedup 1.0000x reference)
//
#include <hip/hip_runtime.h>
#include <hip/hip_bf16.h>

// Decoder: attention is step-invariant (softmax shift-invariance) => ctx
// precomputed once. Persistent kernel runs the 512-step GRU recurrence.
// R14 = TWO INDEPENDENT CHAINS PER WG (latency hiding via interleave):
//  - the 4 rgs are independent recurrences. 128 WGs; WG (sg,cg) runs
//    chains rgA=2sg, rgB=2sg+1 with phase order A-phA,B-phA,A-phB,B-phB.
//    Every flag poll now has one full phase of the OTHER chain's compute
//    between post and poll -> skew+RT off the critical path.
//  - weights shared between chains (same cg) => no extra weight regs
//    (R11's spill trap avoided); +~20 VGPRs of per-chain scalars.
//  - LDS: se2 shared across chains (dead between phases), shA/shB per
//    chain, lds_g/lds_p shared (phase-local) => ~108KB < 160KB.
//  - per-chain protocol = R13's proven structure (parity e2+psumB,
//    per-16-source gates in phA, wave-local phB, nt out stores).
//  - STAGE_BLOCK2: row-pair layout (2x512B contiguous global segments;
//    both rows in the same swizzle class => contiguous LDS writes, free
//    per bank rules; fixes R13's 16-scattered-rows stage that pushed
//    SQ_LDS_BANK_CONFLICT 1.24e8 -> 1.91e8).
// Lessons: R5 poll cheap/load once; R8 no whole-cache fences; R10 no
// plain-store publish; R11 weight residency pins 256thr/WG; R13 barrier
// count is not the lever -- exposed latency is.

#define HH 1024
#define BB 64
#define LL 512
#define VV 1024

typedef short bf16x8 __attribute__((ext_vector_type(8)));
typedef float f32x4 __attribute__((ext_vector_type(4)));

__device__ __forceinline__ short f2bf(float x) {
  union { float f; unsigned u; } a; a.f = x;
  unsigned r = (a.u + 0x7FFF + ((a.u >> 16) & 1)) >> 16;
  return (short)r;
}

__device__ __forceinline__ float fsig(float x) {      // sigmoid, saturation-safe
  return 1.0f / (1.0f + __expf(-x));
}
__device__ __forceinline__ float ftanh(float x) {     // tanh, saturation-safe
  float ex = __expf(2.0f * x);
  return 1.0f - 2.0f / (ex + 1.0f);
}

// ---- coherent (cross-XCD, L3-point) access helpers ----
__device__ __forceinline__ unsigned long long ld64c(const void* p) {
  return __hip_atomic_load((const unsigned long long*)p, __ATOMIC_RELAXED, __HIP_MEMORY_SCOPE_AGENT);
}
__device__ __forceinline__ unsigned ld32c(const void* p) {
  return __hip_atomic_load((const unsigned*)p, __ATOMIC_RELAXED, __HIP_MEMORY_SCOPE_AGENT);
}
__device__ __forceinline__ void st32c(void* p, unsigned v) {
  __hip_atomic_store((unsigned*)p, v, __ATOMIC_RELAXED, __HIP_MEMORY_SCOPE_AGENT);
}
__device__ __forceinline__ void stfc(float* p, float v) {
  union { float f; unsigned u; } a; a.f = v;
  st32c(p, a.u);
}

// ---------------- workspace layout (bytes) ----------------
// FLAGS: 4 rg * 64 cg * 128B (one line per WG) = 32 KB
static constexpr size_t OFF_VE    = 0;                       // 1024 f32
static constexpr size_t OFF_ES    = 4096;                    // 64*512 f32
static constexpr size_t OFF_A     = OFF_ES    + 131072;      // 64*512 f32
static constexpr size_t OFF_CTX   = OFF_A     + 131072;      // 64*1024 f32
static constexpr size_t OFF_GICTX = OFF_CTX   + 262144;      // 64*3072 f32
static constexpr size_t OFF_OC    = OFF_GICTX + 786432;      // 64*1024 f32
static constexpr size_t OFF_FLAGS = OFF_OC    + 262144;      // 8192 u32 (one/128B)
static constexpr size_t OFF_PSUMB = OFF_FLAGS + 32768;       // 2 x 4096 f32 (parity)
static constexpr size_t OFF_PSUMO = OFF_PSUMB + 32768;       // 4rg*16row*64cg f32
static constexpr size_t OFF_E2A   = OFF_PSUMO + 16384;       // 64*1024 bf16 (EB0)
static constexpr size_t OFF_HB    = OFF_E2A   + 131072;      // 64*1024 bf16 (h)
static constexpr size_t OFF_E2B   = OFF_HB    + 131072;      // 64*1024 bf16 (EB1)
static constexpr size_t OFF_PACKW = OFF_E2B   + 131072;      // 18 MB packed weights

// ---------------- precompute kernels ----------------

__global__ void K_init(const float* __restrict__ hidden, const float* __restrict__ dec0,
                       short* __restrict__ hb, short* __restrict__ e2a,
                       unsigned* __restrict__ flags) {
  int tid = blockIdx.x * 256 + threadIdx.x;  // grid 256 -> 65536 threads
  if (tid < BB * HH) {
    hb[tid] = f2bf(hidden[tid]);
    e2a[tid] = f2bf(dec0[tid]);
  }
  if (tid < 8192) flags[tid] = 0u;
}

__global__ void K_ve(const float* __restrict__ Wa, const float* __restrict__ v, float* __restrict__ ve) {
  int i = blockIdx.x * 64 + threadIdx.x;  // 1024 threads
  float acc = 0.f;
  for (int k = 0; k < HH; ++k) acc += Wa[(size_t)k * 2048 + 1024 + i] * v[k];
  ve[i] = acc;
}

__global__ void K_escore(const float* __restrict__ enc, const float* __restrict__ ve, float* __restrict__ es) {
  int bid = blockIdx.x;           // 0..32767 = l*64+b
  int lane = threadIdx.x;         // 64
  const float* row = enc + (size_t)bid * HH;
  float acc = 0.f;
  #pragma unroll
  for (int i = 0; i < 16; ++i) { int k = lane + 64 * i; acc += row[k] * ve[k]; }
  for (int m = 1; m < 64; m <<= 1) acc += __shfl_xor(acc, m);
  if (lane == 0) { int l = bid >> 6, b = bid & 63; es[b * LL + l] = acc; }
}

__global__ void K_asm(const float* __restrict__ es, float* __restrict__ a) {
  __shared__ float red[256];
  int b = blockIdx.x, tid = threadIdx.x;
  float e0 = es[b * LL + tid], e1 = es[b * LL + 256 + tid];
  red[tid] = fmaxf(e0, e1);
  __syncthreads();
  for (int s = 128; s > 0; s >>= 1) { if (tid < s) red[tid] = fmaxf(red[tid], red[tid + s]); __syncthreads(); }
  float M = red[0];
  __syncthreads();
  float x0 = expf(e0 - M), x1 = expf(e1 - M);
  red[tid] = x0 + x1;
  __syncthreads();
  for (int s = 128; s > 0; s >>= 1) { if (tid < s) red[tid] += red[tid + s]; __syncthreads(); }
  float S = red[0];
  a[b * LL + tid] = x0 / S;
  a[b * LL + 256 + tid] = x1 / S;
}

__global__ void K_ctx(const float* __restrict__ enc, const float* __restrict__ a, float* __restrict__ ctx) {
  int b = blockIdx.x >> 3, hc = blockIdx.x & 7;  // 512 blocks, 128 thr
  int h = hc * 128 + threadIdx.x;
  float acc = 0.f;
  for (int l = 0; l < LL; ++l) acc += a[b * LL + l] * enc[(size_t)(l * BB + b) * HH + h];
  ctx[b * HH + h] = acc;
}

__global__ void K_gictx(const float* __restrict__ ctx, const float* __restrict__ W_ih, const float* __restrict__ b_ih,
                        const float* __restrict__ Wo, const float* __restrict__ bo,
                        float* __restrict__ gictx, float* __restrict__ oc) {
  int c = blockIdx.x;      // 4096 blocks
  int b = threadIdx.x;     // 64 threads
  float acc = 0.f;
  if (c < 3072) {
    for (int k = 0; k < HH; ++k) acc += ctx[b * HH + k] * W_ih[(size_t)c * 2048 + 1024 + k];
    gictx[b * 3072 + c] = acc + b_ih[c];
  } else {
    int c2 = c - 3072;
    for (int k = 0; k < HH; ++k) acc += ctx[b * HH + k] * Wo[(size_t)c2 * 3072 + 2048 + k];
    oc[b * HH + c2] = acc + bo[c2];
  }
}

// Pack weights into MFMA B-fragment layout, bf16.
// tiles per col-group cg (16 cols): 0:gi_r(W1) 1:gi_z 2:gi_n 3:Wo_d 4:gh_r(Whh) 5:gh_z 6:gh_n 7:Wf 8:Wo_h
__global__ void K_pack(const float* __restrict__ W_ih, const float* __restrict__ W_hh,
                       const float* __restrict__ Wo, const float* __restrict__ Wf, short* __restrict__ packW) {
  int tid = blockIdx.x * 64 + threadIdx.x;   // 64*9*32*64 = 1,179,648
  int lane = tid & 63;
  int ks = (tid >> 6) & 31;
  int tile = (tid >> 11) % 9;
  int cg = tid / (9 * 32 * 64);
  int n = lane & 15;
  int k0 = ks * 32 + (lane >> 4) * 8;
  int row = cg * 16 + n;
  const float* src;
  size_t base;
  switch (tile) {
    case 0: base = (size_t)row * 2048;               src = W_ih; break;
    case 1: base = (size_t)(1024 + row) * 2048;      src = W_ih; break;
    case 2: base = (size_t)(2048 + row) * 2048;      src = W_ih; break;
    case 3: base = (size_t)row * 3072 + 1024;        src = Wo;   break;
    case 4: base = (size_t)row * 1024;               src = W_hh; break;
    case 5: base = (size_t)(1024 + row) * 1024;      src = W_hh; break;
    case 6: base = (size_t)(2048 + row) * 1024;      src = W_hh; break;
    case 7: base = (size_t)row * 1024;               src = Wf;   break;
    default: base = (size_t)row * 3072;              src = Wo;   break;
  }
  bf16x8 vv;
  #pragma unroll
  for (int j = 0; j < 8; ++j) vv[j] = f2bf(src[base + k0 + j]);
  ((bf16x8*)packW)[tid] = vv;
}

// ---------------- persistent step kernel ----------------

// Stage one 16-row x 256-col (16-cg) block into LDS with XOR-swizzle
// byte_col ^= ((row&7)<<4). Lane (rr=lane>>5, cl=lane&31): rows rr*8+i,
// 16B at col cl within the block's 512B row-span -> per instruction
// 2x512B contiguous global segments and same-swizzle-class LDS rows
// (contiguous 512B per row => conflict-free writes).
#define STAGE_BLOCK2(dst, srcbase, blk)                                        \
  do {                                                                         \
    const int rr_ = lane >> 5;                                                 \
    const int cl_ = lane & 31;                                                 \
    const short* pb_ = (srcbase) + (rr_ << 13) + ((blk) << 8) + (cl_ << 3);    \
    f32x4 t0_, t1_, t2_, t3_, t4_, t5_, t6_, t7_;                              \
    asm volatile(                                                              \
      "global_load_dwordx4 %0, %8, off sc0 sc1\n\t"                            \
      "global_load_dwordx4 %1, %8, off offset:2048 sc0 sc1\n\t"                \
      "global_load_dwordx4 %2, %9, off sc0 sc1\n\t"                            \
      "global_load_dwordx4 %3, %9, off offset:2048 sc0 sc1\n\t"                \
      "global_load_dwordx4 %4, %10, off sc0 sc1\n\t"                           \
      "global_load_dwordx4 %5, %10, off offset:2048 sc0 sc1\n\t"               \
      "global_load_dwordx4 %6, %11, off sc0 sc1\n\t"                           \
      "global_load_dwordx4 %7, %11, off offset:2048 sc0 sc1\n\t"               \
      "s_waitcnt vmcnt(0)"                                                     \
      : "=&v"(t0_), "=&v"(t1_), "=&v"(t2_), "=&v"(t3_),                        \
        "=&v"(t4_), "=&v"(t5_), "=&v"(t6_), "=&v"(t7_)                         \
      : "v"(pb_), "v"(pb_ + 2048), "v"(pb_ + 4096), "v"(pb_ + 6144)            \
      : "memory");                                                             \
    f32x4 tv_[8] = {t0_, t1_, t2_, t3_, t4_, t5_, t6_, t7_};                   \
    _Pragma("unroll")                                                          \
    for (int i_ = 0; i_ < 8; ++i_) {                                           \
      int row_ = i_ + rr_ * 8;                                                 \
      int sw_ = (((blk) << 9) + (cl_ << 4)) ^ (i_ << 4);                       \
      *(f32x4*)&(dst)[(row_ << 10) + (sw_ >> 1)] = tv_[i_];                    \
    }                                                                          \
    __builtin_amdgcn_sched_barrier(0);                                         \
  } while (0)

// Poll the 16 source-cg flags of block blk (4-way redundant across lanes).
#define POLL16(flg, blk, ep)                                                   \
  do {                                                                         \
    unsigned f_;                                                               \
    for (;;) {                                                                 \
      f_ = ld32c((flg) + ((blk) * 16 + (lane & 15)) * 32);                     \
      if (!__any(f_ < (unsigned)(ep))) break;                                  \
      __builtin_amdgcn_s_sleep(1);                                             \
    }                                                                          \
  } while (0)

// Poll all 64 flags (one line per lane).
#define POLL64(flg, ep)                                                        \
  do {                                                                         \
    unsigned f_;                                                               \
    for (;;) {                                                                 \
      f_ = ld32c((flg) + lane * 32);                                           \
      if (!__any(f_ < (unsigned)(ep))) break;                                  \
      __builtin_amdgcn_s_sleep(1);                                             \
    }                                                                          \
  } while (0)

// MFMA A-fragment read from swizzled LDS slice (conflict-free, 2-way max).
#define LFRAG(buf, ks) \
  (*(const bf16x8*)&(buf)[((llo) << 10) + (((((ks) * 64) + (lhi << 4)) ^ ((llo & 7) << 4)) >> 1)])

// ======== per-chain phase A (stage e2, gates GEMM, GRU, bar1 post) ========
#define PHA(SUF, T)                                                            \
  do {                                                                         \
    const int par_ = (T) & 1;                                                  \
    const short* ebr_ = (par_ ? e2b : e2a) + rg##SUF * 16384;                  \
    unsigned long long pc_[8];                                                 \
    if (wave == 0) {                                                           \
      POLL64(flg##SUF, 2u * (unsigned)(T));                                    \
      if ((T) >= 1) {                                                          \
        const float* pp_ = psumB + par_ * 4096 + rg##SUF * 1024 + llo * 64 + lhi * 16; \
        _Pragma("unroll")                                                      \
        for (int i_ = 0; i_ < 8; ++i_) pc_[i_] = ld64c(pp_ + i_ * 2);          \
      }                                                                        \
      STAGE_BLOCK2(se2, ebr_, blkA);                                           \
    } else {                                                                   \
      POLL16(flg##SUF, blkA, 2u * (unsigned)(T));                              \
      STAGE_BLOCK2(se2, ebr_, blkA);                                           \
    }                                                                          \
    __syncthreads();                                                           \
    if (wave == 0) {                                                           \
      float total_ = 1.0f;                                                     \
      if ((T) >= 1) {                                                          \
        float s_ = 0.f;                                                        \
        _Pragma("unroll")                                                      \
        for (int i_ = 0; i_ < 8; ++i_) {                                       \
          union { unsigned long long u; float f[2]; } c_; c_.u = pc_[i_];      \
          s_ += c_.f[0] + c_.f[1];                                             \
        }                                                                      \
        s_ += __shfl_xor(s_, 16); s_ += __shfl_xor(s_, 32);                    \
        total_ = s_;                                                           \
      }                                                                        \
      if (lane < 16) rs##SUF[lane] = 1.0f / total_;                            \
    }                                                                          \
    const short* A0_ = (wave < 2) ? se2 : sh##SUF;                             \
    f32x4 acc0_ = {0.f, 0.f, 0.f, 0.f}, acc1_ = {0.f, 0.f, 0.f, 0.f};          \
    _Pragma("unroll")                                                          \
    for (int ks_ = 0; ks_ < 32; ++ks_) {                                       \
      bf16x8 af0_ = LFRAG(A0_, ks_);                                           \
      bf16x8 af1_ = (wave == 3) ? LFRAG(se2, ks_) : af0_;                      \
      acc0_ = __builtin_amdgcn_mfma_f32_16x16x32_bf16(af0_, wA0[ks_], acc0_, 0, 0, 0); \
      acc1_ = __builtin_amdgcn_mfma_f32_16x16x32_bf16(af1_, wA1[ks_], acc1_, 0, 0, 0); \
    }                                                                          \
    if (wave == 0) {                                                           \
      _Pragma("unroll")                                                        \
      for (int r_ = 0; r_ < 4; ++r_) { lds_g[0][lhi*4+r_][llo] = acc0_[r_]; lds_g[1][lhi*4+r_][llo] = acc1_[r_]; } \
    } else if (wave == 1) {                                                    \
      _Pragma("unroll")                                                        \
      for (int r_ = 0; r_ < 4; ++r_) { lds_g[2][lhi*4+r_][llo] = acc0_[r_]; savedA2##SUF[r_] = acc1_[r_]; } \
    } else if (wave == 2) {                                                    \
      _Pragma("unroll")                                                        \
      for (int r_ = 0; r_ < 4; ++r_) { lds_g[3][lhi*4+r_][llo] = acc0_[r_]; lds_g[4][lhi*4+r_][llo] = acc1_[r_]; } \
    } else {                                                                   \
      _Pragma("unroll")                                                        \
      for (int r_ = 0; r_ < 4; ++r_) lds_g[5][lhi*4+r_][llo] = acc0_[r_];      \
    }                                                                          \
    __syncthreads();                                                           \
    if (wave == 3 && (T) >= 1) {                                               \
      _Pragma("unroll")                                                        \
      for (int r_ = 0; r_ < 4; ++r_) eo##SUF[r_] = __expf(acc1_[r_] * rs##SUF[lhi*4+r_] + c_bf); \
      _Pragma("unroll")                                                        \
      for (int r_ = 0; r_ < 4; ++r_) {                                         \
        float v_ = eo##SUF[r_];                                                \
        v_ += __shfl_xor(v_, 1, 16); v_ += __shfl_xor(v_, 2, 16);              \
        v_ += __shfl_xor(v_, 4, 16); v_ += __shfl_xor(v_, 8, 16);              \
        if (llo == 0) stfc(psumO + rg##SUF * 1024 + (lhi*4+r_) * 64 + cg, v_); \
      }                                                                        \
    }                                                                          \
    {                                                                          \
      float rsr_ = rs##SUF[row];                                               \
      float gr_  = lds_g[0][row][col] * rsr_ + lds_g[3][row][col] + cgr##SUF;  \
      float gz_  = lds_g[1][row][col] * rsr_ + lds_g[4][row][col] + cgz##SUF;  \
      float gin_ = lds_g[2][row][col] * rsr_ + cgn##SUF;                       \
      float ghn_ = lds_g[5][row][col] + cghn##SUF;                             \
      float rg_g = fsig(gr_);                                                  \
      float zz_ = fsig(gz_);                                                   \
      float nn_ = ftanh(gin_ + rg_g * ghn_);                                   \
      float hnew_ = (1.0f - zz_) * nn_ + zz_ * hreg##SUF;                      \
      hreg##SUF = hnew_;                                                       \
      unsigned short hv_ = (unsigned short)f2bf(hnew_);                        \
      int other_ = __shfl_xor((int)hv_, 1);                                    \
      if ((col & 1) == 0) {                                                    \
        unsigned pk_ = (unsigned)hv_ | ((unsigned)(unsigned short)other_ << 16); \
        st32c(hb + b##SUF * HH + (j & ~1), pk_);                               \
      }                                                                        \
    }                                                                          \
    __syncthreads();                                                           \
    if (tid == 0) st32c(flg##SUF + cg * 32, 2u * (unsigned)(T) + 1u);          \
  } while (0)

// ======== per-chain phase B (wave-local h stage, Wo_h GEMM, e2 posts) ======
#define PHB(SUF, T)                                                            \
  do {                                                                         \
    const int par_ = (T) & 1;                                                  \
    short* ebw_ = (par_ ? e2a : e2b);                                          \
    float* PBw_ = psumB + (par_ ^ 1) * 4096 + rg##SUF * 1024;                  \
    union { unsigned long long u; float f[2]; } g0_[4], g1_[4];                \
    if (wave == 3) {                                                           \
      POLL64(flg##SUF, 2u * (unsigned)(T) + 1u);                               \
      STAGE_BLOCK2(sh##SUF, hs##SUF, 3);                                       \
      if ((T) >= 1) {                                                          \
        _Pragma("unroll")                                                      \
        for (int r_ = 0; r_ < 4; ++r_) {                                       \
          const float* pp_ = psumO + rg##SUF * 1024 + (lhi*4+r_) * 64 + llo * 4; \
          g0_[r_].u = ld64c(pp_);                                              \
          g1_[r_].u = ld64c(pp_ + 2);                                          \
        }                                                                      \
      }                                                                        \
    } else {                                                                   \
      POLL16(flg##SUF, wave, 2u * (unsigned)(T) + 1u);                         \
      STAGE_BLOCK2(sh##SUF, hs##SUF, wave);                                    \
    }                                                                          \
    f32x4 accB_ = {0.f, 0.f, 0.f, 0.f};                                        \
    _Pragma("unroll")                                                          \
    for (int i_ = 0; i_ < 8; ++i_) {                                           \
      int ks_ = wave * 8 + i_;                                                 \
      bf16x8 af_ = LFRAG(sh##SUF, ks_);                                        \
      accB_ = __builtin_amdgcn_mfma_f32_16x16x32_bf16(af_, wB8[i_], accB_, 0, 0, 0); \
    }                                                                          \
    _Pragma("unroll")                                                          \
    for (int r_ = 0; r_ < 4; ++r_) lds_p[wave][lhi*4+r_][llo] = accB_[r_];     \
    if (wave == 1) {                                                           \
      _Pragma("unroll")                                                        \
      for (int r_ = 0; r_ < 4; ++r_) lds_p[4][lhi*4+r_][llo] = savedA2##SUF[r_]; \
    }                                                                          \
    __syncthreads();                                                           \
    {                                                                          \
      float rsr_ = rs##SUF[row];                                               \
      float l2_ = lds_p[0][row][col] + lds_p[1][row][col] + lds_p[2][row][col] \
                + lds_p[3][row][col] + lds_p[4][row][col] * rsr_ + coc##SUF;   \
      float ev_ = __expf(l2_);                                                 \
      unsigned short eb_ = (unsigned short)f2bf(ev_);                          \
      int other_ = __shfl_xor((int)eb_, 1);                                    \
      if ((col & 1) == 0) {                                                    \
        unsigned pk_ = (unsigned)eb_ | ((unsigned)(unsigned short)other_ << 16); \
        st32c(ebw_ + b##SUF * HH + (j & ~1), pk_);                             \
      }                                                                        \
      float sv_ = ev_;                                                         \
      sv_ += __shfl_xor(sv_, 1, 16); sv_ += __shfl_xor(sv_, 2, 16);            \
      sv_ += __shfl_xor(sv_, 4, 16); sv_ += __shfl_xor(sv_, 8, 16);            \
      if (col == 0) stfc(PBw_ + row * 64 + cg, sv_);                           \
    }                                                                          \
    if (wave == 3 && (T) >= 1) {                                               \
      _Pragma("unroll")                                                        \
      for (int r_ = 0; r_ < 4; ++r_) {                                         \
        float s_ = g0_[r_].f[0] + g0_[r_].f[1] + g1_[r_].f[0] + g1_[r_].f[1];  \
        s_ += __shfl_xor(s_, 1, 16); s_ += __shfl_xor(s_, 2, 16);              \
        s_ += __shfl_xor(s_, 4, 16); s_ += __shfl_xor(s_, 8, 16);              \
        int b2_ = rg##SUF * 16 + lhi * 4 + r_;                                 \
        __builtin_nontemporal_store(eo##SUF[r_] / s_,                          \
          &outp[(size_t)((T) - 1) * BB * VV + (size_t)b2_ * VV + cg * 16 + llo]); \
      }                                                                        \
    }                                                                          \
    __syncthreads();                                                           \
    if (tid == 0) st32c(flg##SUF + cg * 32, 2u * (unsigned)(T) + 2u);          \
  } while (0)

// ======== per-chain tail: emit out(LL-1) ========
#define TAILE(SUF)                                                             \
  do {                                                                         \
    if (wave == 3) {                                                           \
      POLL64(flg##SUF, 2u * (unsigned)LL + 1u);                                \
      _Pragma("unroll")                                                        \
      for (int r_ = 0; r_ < 4; ++r_) {                                         \
        const float* pp_ = psumO + rg##SUF * 1024 + (lhi*4+r_) * 64 + llo * 4; \
        union { unsigned long long u; float f[2]; } c0_, c1_;                  \
        c0_.u = ld64c(pp_); c1_.u = ld64c(pp_ + 2);                            \
        float s_ = c0_.f[0] + c0_.f[1] + c1_.f[0] + c1_.f[1];                  \
        s_ += __shfl_xor(s_, 1, 16); s_ += __shfl_xor(s_, 2, 16);              \
        s_ += __shfl_xor(s_, 4, 16); s_ += __shfl_xor(s_, 8, 16);              \
        int b2_ = rg##SUF * 16 + lhi * 4 + r_;                                 \
        outp[(size_t)(LL - 1) * BB * VV + (size_t)b2_ * VV + cg * 16 + llo] = eo##SUF[r_] / s_; \
      }                                                                        \
    }                                                                          \
  } while (0)

__global__ __launch_bounds__(256, 1) void K_step(
    const bf16x8* __restrict__ packW,
    short* __restrict__ e2a, short* __restrict__ e2b,
    short* __restrict__ hb,
    const float* __restrict__ hidden,
    float* __restrict__ psumB, float* __restrict__ psumO,
    const float* __restrict__ gictx, const float* __restrict__ ocbuf,
    const float* __restrict__ b_hh, const float* __restrict__ bfv,
    float* __restrict__ outp, unsigned* __restrict__ flags) {
  const int wg = blockIdx.x;      // 128 WGs
  const int sg = wg & 1;          // supergroup -> chains rgA=2sg, rgB=2sg+1
  const int cg = wg >> 1;         // col group [0,64)
  const int rgA = sg * 2, rgB = sg * 2 + 1;
  const int tid = threadIdx.x;
  const int wave = tid >> 6;
  const int lane = tid & 63;
  const int lhi = lane >> 4;
  const int llo = lane & 15;
  const int blkA = (wave + cg) & 3;   // rotated source block for A-stages

  __shared__ short se2[16 * 1024];    // shared e2 slice (phase-local)
  __shared__ short shA[16 * 1024];    // chain-A h slice
  __shared__ short shB[16 * 1024];    // chain-B h slice
  __shared__ float lds_g[6][16][17];  // phase-local gate accs
  __shared__ float lds_p[5][16][17];  // phase-local phase-B partials
  __shared__ float rsA[16], rsB[16];  // per-chain 1/rowsum

  const int wbase = cg * (9 * 32 * 64) + lane;
  const int t0 = wave * 2, t1 = wave * 2 + 1;

  // ---- load step-invariant weights (shared by both chains), pin them ----
  bf16x8 wA0[32], wA1[32], wB8[8];
  #pragma unroll
  for (int ks = 0; ks < 32; ++ks) {
    wA0[ks] = packW[wbase + (t0 * 32 + ks) * 64];
    wA1[ks] = packW[wbase + (t1 * 32 + ks) * 64];
  }
  #pragma unroll
  for (int i = 0; i < 8; ++i) wB8[i] = packW[wbase + (8 * 32 + wave * 8 + i) * 64];
  #pragma unroll
  for (int ks = 0; ks < 32; ++ks) {
    asm volatile("" : "+v"(wA0[ks]));
    asm volatile("" : "+v"(wA1[ks]));
  }
  #pragma unroll
  for (int i = 0; i < 8; ++i) asm volatile("" : "+v"(wB8[i]));

  // ---- per-chain step-invariant scalars; h carried in-register ----
  const int row = tid >> 4, col = tid & 15;
  const int bA = rgA * 16 + row, bB = rgB * 16 + row, j = cg * 16 + col;
  const float cgrA  = gictx[bA * 3072 + j]        + b_hh[j];
  const float cgzA  = gictx[bA * 3072 + 1024 + j] + b_hh[1024 + j];
  const float cgnA  = gictx[bA * 3072 + 2048 + j];
  const float cghnA = b_hh[2048 + j];
  const float cocA  = ocbuf[bA * HH + j];
  float hregA = hidden[bA * HH + j];
  const float cgrB  = gictx[bB * 3072 + j]        + b_hh[j];
  const float cgzB  = gictx[bB * 3072 + 1024 + j] + b_hh[1024 + j];
  const float cgnB  = gictx[bB * 3072 + 2048 + j];
  const float cghnB = cghnA;
  const float cocB  = ocbuf[bB * HH + j];
  float hregB = hidden[bB * HH + j];
  const float c_bf  = bfv[cg * 16 + llo];

  unsigned* flgA = flags + rgA * (64 * 32);
  unsigned* flgB = flags + rgB * (64 * 32);
  short* hsA = hb + rgA * 16384;
  short* hsB = hb + rgB * 16384;

  f32x4 savedA2A = {0.f,0.f,0.f,0.f}, savedA2B = {0.f,0.f,0.f,0.f};
  f32x4 eoA = {0.f,0.f,0.f,0.f}, eoB = {0.f,0.f,0.f,0.f};

  // pre-stage h(0) for both chains (block = wave covers all 4 blocks)
  STAGE_BLOCK2(shA, hsA, wave);
  STAGE_BLOCK2(shB, hsB, wave);
  __syncthreads();

  for (int t = 0; t < LL; ++t) {
    PHA(A, t);
    PHA(B, t);
    PHB(A, t);
    PHB(B, t);
  }
  // t == LL: phase A only (computes eo(LL) = out(LL-1) logits), then emit
  PHA(A, LL);
  PHA(B, LL);
  TAILE(A);
  TAILE(B);
}

// ---------------- host launcher ----------------

extern "C" void kernel_launch(void* const* d_in, const int* in_sizes, int n_in,
                              void* d_out, int out_size, void* d_ws, size_t ws_size,
                              hipStream_t stream) {
  (void)in_sizes; (void)n_in; (void)out_size; (void)ws_size;
  const float* enc    = (const float*)d_in[0];
  const float* hidden = (const float*)d_in[1];
  const float* dec0   = (const float*)d_in[2];
  const float* Wa     = (const float*)d_in[3];
  // d_in[4] = ba: unused (softmax shift-invariance)
  const float* v      = (const float*)d_in[5];
  const float* W_ih   = (const float*)d_in[6];
  const float* b_ih   = (const float*)d_in[7];
  const float* W_hh   = (const float*)d_in[8];
  const float* b_hh   = (const float*)d_in[9];
  const float* Wo     = (const float*)d_in[10];
  const float* bo     = (const float*)d_in[11];
  const float* Wf     = (const float*)d_in[12];
  const float* bfv    = (const float*)d_in[13];

  char* ws = (char*)d_ws;
  float* ve    = (float*)(ws + OFF_VE);
  float* es    = (float*)(ws + OFF_ES);
  float* attn  = (float*)(ws + OFF_A);
  float* ctx   = (float*)(ws + OFF_CTX);
  float* gictx = (float*)(ws + OFF_GICTX);
  float* oc    = (float*)(ws + OFF_OC);
  unsigned* flags = (unsigned*)(ws + OFF_FLAGS);
  float* psumB = (float*)(ws + OFF_PSUMB);
  float* psumO = (float*)(ws + OFF_PSUMO);
  short* e2a   = (short*)(ws + OFF_E2A);
  short* e2b   = (short*)(ws + OFF_E2B);
  short* hb    = (short*)(ws + OFF_HB);
  short* packW = (short*)(ws + OFF_PACKW);

  hipLaunchKernelGGL(K_init, dim3(256), dim3(256), 0, stream, hidden, dec0, hb, e2a, flags);
  hipLaunchKernelGGL(K_ve, dim3(16), dim3(64), 0, stream, Wa, v, ve);
  hipLaunchKernelGGL(K_escore, dim3(LL * BB), dim3(64), 0, stream, enc, ve, es);
  hipLaunchKernelGGL(K_asm, dim3(BB), dim3(256), 0, stream, es, attn);
  hipLaunchKernelGGL(K_ctx, dim3(512), dim3(128), 0, stream, enc, attn, ctx);
  hipLaunchKernelGGL(K_gictx, dim3(4096), dim3(64), 0, stream, ctx, W_ih, b_ih, Wo, bo, gictx, oc);
  hipLaunchKernelGGL(K_pack, dim3(64 * 9 * 32), dim3(64), 0, stream, W_ih, W_hh, Wo, Wf, packW);
  hipLaunchKernelGGL(K_step, dim3(128), dim3(256), 0, stream,
                     (const bf16x8*)packW, e2a, e2b, hb, hidden, psumB, psumO,
                     gictx, oc, b_hh, bfv, (float*)d_out, flags);
}

// Round 11
// 5036.066 us; speedup vs baseline: 2.9787x; 2.9787x over previous
//
#include <hip/hip_runtime.h>
#include <hip/hip_bf16.h>

// Decoder: attention is step-invariant (softmax shift-invariance) => ctx
// precomputed once. Persistent kernel runs the 512-step GRU recurrence.
// R15 = REVERT to R9 (best verified: 5040us, best dispatch 4835).
// Failed-structure ledger (all reverted):
//  R5  value-polling: retry unit = 8KB volley -> 2x fetch, +RTs.
//  R8  agent fences: full L2 wb/inv per barrier -> 2x.
//  R10 XCD two-tier: plain stores don't publish to L3 -> deadlock.
//  R11 512-thr WG: 2 waves/SIMD = 256-reg budget < 288 weight regs -> spill.
//  R12/R13 per-wave gated stages: neutral (barrier count not the lever).
//  R14 2-chain interleave: program-order serializes; latencies ADD.
// R9 = R7 protocol + (a) 16B sc0sc1 burst stages (halved request count),
// (b) wave->chunk rotation (anti-convoy), (c) s_sleep poll backoff,
// (d) per-128B-line flags (R7), (e) psumB-reduce-after-sync1 (R7),
// (f) out(t-1) in bar2 poll shadow + __expf fast math (R6).
// Remaining structure: 512 serial steps x 2 cross-XCD exchanges, each a
// poll-RT + 32KB x 64-WG L3 broadcast; <=1 WG/CU pinned by 288 weight regs.

#define HH 1024
#define BB 64
#define LL 512
#define VV 1024

typedef short bf16x8 __attribute__((ext_vector_type(8)));
typedef float f32x4 __attribute__((ext_vector_type(4)));

__device__ __forceinline__ short f2bf(float x) {
  union { float f; unsigned u; } a; a.f = x;
  unsigned r = (a.u + 0x7FFF + ((a.u >> 16) & 1)) >> 16;
  return (short)r;
}

__device__ __forceinline__ float fsig(float x) {      // sigmoid, saturation-safe
  return 1.0f / (1.0f + __expf(-x));
}
__device__ __forceinline__ float ftanh(float x) {     // tanh, saturation-safe
  float ex = __expf(2.0f * x);
  return 1.0f - 2.0f / (ex + 1.0f);
}

// ---- coherent (cross-XCD, L3-point) access helpers ----
__device__ __forceinline__ unsigned long long ld64c(const void* p) {
  return __hip_atomic_load((const unsigned long long*)p, __ATOMIC_RELAXED, __HIP_MEMORY_SCOPE_AGENT);
}
__device__ __forceinline__ unsigned ld32c(const void* p) {
  return __hip_atomic_load((const unsigned*)p, __ATOMIC_RELAXED, __HIP_MEMORY_SCOPE_AGENT);
}
__device__ __forceinline__ void st32c(void* p, unsigned v) {
  __hip_atomic_store((unsigned*)p, v, __ATOMIC_RELAXED, __HIP_MEMORY_SCOPE_AGENT);
}
__device__ __forceinline__ void stfc(float* p, float v) {
  union { float f; unsigned u; } a; a.f = v;
  st32c(p, a.u);
}

// ---------------- workspace layout (bytes) ----------------
// FLAGS: 4 rg * 64 cg * 128B (one line per WG) = 32 KB
static constexpr size_t OFF_VE    = 0;                       // 1024 f32
static constexpr size_t OFF_ES    = 4096;                    // 64*512 f32
static constexpr size_t OFF_A     = OFF_ES    + 131072;      // 64*512 f32
static constexpr size_t OFF_CTX   = OFF_A     + 131072;      // 64*1024 f32
static constexpr size_t OFF_GICTX = OFF_CTX   + 262144;      // 64*3072 f32
static constexpr size_t OFF_OC    = OFF_GICTX + 786432;      // 64*1024 f32
static constexpr size_t OFF_FLAGS = OFF_OC    + 262144;      // 8192 u32 (one/128B)
static constexpr size_t OFF_PSUMB = OFF_FLAGS + 32768;       // 4rg*16row*64cg f32
static constexpr size_t OFF_PSUMO = OFF_PSUMB + 16384;       // 4rg*16row*64cg f32
static constexpr size_t OFF_E2    = OFF_PSUMO + 16384;       // 64*1024 bf16
static constexpr size_t OFF_HB0   = OFF_E2    + 131072;      // 64*1024 bf16
static constexpr size_t OFF_HB1   = OFF_HB0   + 131072;      // (unused)
static constexpr size_t OFF_PACKW = OFF_HB1   + 131072;      // 18 MB packed weights

// ---------------- precompute kernels ----------------

__global__ void K_init(const float* __restrict__ hidden, const float* __restrict__ dec0,
                       short* __restrict__ hb, short* __restrict__ e2,
                       unsigned* __restrict__ flags) {
  int tid = blockIdx.x * 256 + threadIdx.x;  // grid 256 -> 65536 threads
  if (tid < BB * HH) {
    hb[tid] = f2bf(hidden[tid]);
    e2[tid] = f2bf(dec0[tid]);
  }
  if (tid < 8192) flags[tid] = 0u;
}

__global__ void K_ve(const float* __restrict__ Wa, const float* __restrict__ v, float* __restrict__ ve) {
  int i = blockIdx.x * 64 + threadIdx.x;  // 1024 threads
  float acc = 0.f;
  for (int k = 0; k < HH; ++k) acc += Wa[(size_t)k * 2048 + 1024 + i] * v[k];
  ve[i] = acc;
}

__global__ void K_escore(const float* __restrict__ enc, const float* __restrict__ ve, float* __restrict__ es) {
  int bid = blockIdx.x;           // 0..32767 = l*64+b
  int lane = threadIdx.x;         // 64
  const float* row = enc + (size_t)bid * HH;
  float acc = 0.f;
  #pragma unroll
  for (int i = 0; i < 16; ++i) { int k = lane + 64 * i; acc += row[k] * ve[k]; }
  for (int m = 1; m < 64; m <<= 1) acc += __shfl_xor(acc, m);
  if (lane == 0) { int l = bid >> 6, b = bid & 63; es[b * LL + l] = acc; }
}

__global__ void K_asm(const float* __restrict__ es, float* __restrict__ a) {
  __shared__ float red[256];
  int b = blockIdx.x, tid = threadIdx.x;
  float e0 = es[b * LL + tid], e1 = es[b * LL + 256 + tid];
  red[tid] = fmaxf(e0, e1);
  __syncthreads();
  for (int s = 128; s > 0; s >>= 1) { if (tid < s) red[tid] = fmaxf(red[tid], red[tid + s]); __syncthreads(); }
  float M = red[0];
  __syncthreads();
  float x0 = expf(e0 - M), x1 = expf(e1 - M);
  red[tid] = x0 + x1;
  __syncthreads();
  for (int s = 128; s > 0; s >>= 1) { if (tid < s) red[tid] += red[tid + s]; __syncthreads(); }
  float S = red[0];
  a[b * LL + tid] = x0 / S;
  a[b * LL + 256 + tid] = x1 / S;
}

__global__ void K_ctx(const float* __restrict__ enc, const float* __restrict__ a, float* __restrict__ ctx) {
  int b = blockIdx.x >> 3, hc = blockIdx.x & 7;  // 512 blocks, 128 thr
  int h = hc * 128 + threadIdx.x;
  float acc = 0.f;
  for (int l = 0; l < LL; ++l) acc += a[b * LL + l] * enc[(size_t)(l * BB + b) * HH + h];
  ctx[b * HH + h] = acc;
}

__global__ void K_gictx(const float* __restrict__ ctx, const float* __restrict__ W_ih, const float* __restrict__ b_ih,
                        const float* __restrict__ Wo, const float* __restrict__ bo,
                        float* __restrict__ gictx, float* __restrict__ oc) {
  int c = blockIdx.x;      // 4096 blocks
  int b = threadIdx.x;     // 64 threads
  float acc = 0.f;
  if (c < 3072) {
    for (int k = 0; k < HH; ++k) acc += ctx[b * HH + k] * W_ih[(size_t)c * 2048 + 1024 + k];
    gictx[b * 3072 + c] = acc + b_ih[c];
  } else {
    int c2 = c - 3072;
    for (int k = 0; k < HH; ++k) acc += ctx[b * HH + k] * Wo[(size_t)c2 * 3072 + 2048 + k];
    oc[b * HH + c2] = acc + bo[c2];
  }
}

// Pack weights into MFMA B-fragment layout, bf16.
// tiles per col-group cg (16 cols): 0:gi_r(W1) 1:gi_z 2:gi_n 3:Wo_d 4:gh_r(Whh) 5:gh_z 6:gh_n 7:Wf 8:Wo_h
__global__ void K_pack(const float* __restrict__ W_ih, const float* __restrict__ W_hh,
                       const float* __restrict__ Wo, const float* __restrict__ Wf, short* __restrict__ packW) {
  int tid = blockIdx.x * 64 + threadIdx.x;   // 64*9*32*64 = 1,179,648
  int lane = tid & 63;
  int ks = (tid >> 6) & 31;
  int tile = (tid >> 11) % 9;
  int cg = tid / (9 * 32 * 64);
  int n = lane & 15;
  int k0 = ks * 32 + (lane >> 4) * 8;
  int row = cg * 16 + n;
  const float* src;
  size_t base;
  switch (tile) {
    case 0: base = (size_t)row * 2048;               src = W_ih; break;
    case 1: base = (size_t)(1024 + row) * 2048;      src = W_ih; break;
    case 2: base = (size_t)(2048 + row) * 2048;      src = W_ih; break;
    case 3: base = (size_t)row * 3072 + 1024;        src = Wo;   break;
    case 4: base = (size_t)row * 1024;               src = W_hh; break;
    case 5: base = (size_t)(1024 + row) * 1024;      src = W_hh; break;
    case 6: base = (size_t)(2048 + row) * 1024;      src = W_hh; break;
    case 7: base = (size_t)row * 1024;               src = Wf;   break;
    default: base = (size_t)row * 3072;              src = Wo;   break;
  }
  bf16x8 vv;
  #pragma unroll
  for (int j = 0; j < 8; ++j) vv[j] = f2bf(src[base + k0 + j]);
  ((bf16x8*)packW)[tid] = vv;
}

// ---------------- persistent step kernel ----------------

// Stage a 16x1024 bf16 slice (32KB, contiguous in global) into LDS with
// XOR-swizzle: byte_col ^= ((row&7)<<4).
// 16B sc0+sc1 burst loads (one vmcnt(0) per burst), wave->chunk rotation
// by (cg&3) to spread concurrent WGs across distinct lines.
#define STAGE_SLICE(dst, srcbase)                                              \
  do {                                                                         \
    const int chunk_ = (wave + (cg & 3)) & 3;                                  \
    const short* pA_ = (srcbase) + (chunk_ << 12) + (lane << 3);               \
    const short* pB_ = pA_ + 2048;                                             \
    f32x4 t0_, t1_, t2_, t3_, t4_, t5_, t6_, t7_;                              \
    asm volatile(                                                              \
      "global_load_dwordx4 %0, %8, off sc0 sc1\n\t"                            \
      "global_load_dwordx4 %1, %8, off offset:1024 sc0 sc1\n\t"                \
      "global_load_dwordx4 %2, %8, off offset:2048 sc0 sc1\n\t"                \
      "global_load_dwordx4 %3, %8, off offset:3072 sc0 sc1\n\t"                \
      "global_load_dwordx4 %4, %9, off sc0 sc1\n\t"                            \
      "global_load_dwordx4 %5, %9, off offset:1024 sc0 sc1\n\t"                \
      "global_load_dwordx4 %6, %9, off offset:2048 sc0 sc1\n\t"                \
      "global_load_dwordx4 %7, %9, off offset:3072 sc0 sc1\n\t"                \
      "s_waitcnt vmcnt(0)"                                                     \
      : "=&v"(t0_), "=&v"(t1_), "=&v"(t2_), "=&v"(t3_),                        \
        "=&v"(t4_), "=&v"(t5_), "=&v"(t6_), "=&v"(t7_)                         \
      : "v"(pA_), "v"(pB_)                                                     \
      : "memory");                                                             \
    f32x4 tv_[8] = {t0_, t1_, t2_, t3_, t4_, t5_, t6_, t7_};                   \
    _Pragma("unroll")                                                          \
    for (int i_ = 0; i_ < 8; ++i_) {                                           \
      int off_ = (chunk_ << 12) + (i_ << 9) + (lane << 3);                     \
      int r_ = off_ >> 10;                                                     \
      int sw_ = ((off_ & 1023) << 1) ^ ((r_ & 7) << 4);                        \
      *(f32x4*)&(dst)[(r_ << 10) + (sw_ >> 1)] = tv_[i_];                      \
    }                                                                          \
    __builtin_amdgcn_sched_barrier(0);                                         \
  } while (0)

// MFMA A-fragment read from swizzled LDS slice: lane l -> row llo, k-bytes
// ks*64 + lhi*16, XOR'd by ((row&7)<<4). Conflict-free (2-way max).
#define LFRAG(buf, ks) \
  (*(const bf16x8*)&(buf)[((llo) << 10) + (((((ks) * 64) + (lhi << 4)) ^ ((llo & 7) << 4)) >> 1)])

__global__ __launch_bounds__(256, 1) void K_step(
    const bf16x8* __restrict__ packW,
    short* __restrict__ e2, short* __restrict__ hb,
    const float* __restrict__ hidden,
    float* __restrict__ psumB, float* __restrict__ psumO,
    const float* __restrict__ gictx, const float* __restrict__ ocbuf,
    const float* __restrict__ b_hh, const float* __restrict__ bfv,
    float* __restrict__ outp, unsigned* __restrict__ flags) {
  const int wg = blockIdx.x;
  const int rg = wg & 3;      // row group: rows [16rg,16rg+16)
  const int cg = wg >> 2;     // col group: 16 cols of each output tile
  const int tid = threadIdx.x;
  const int wave = tid >> 6;
  const int lane = tid & 63;
  const int lhi = lane >> 4;
  const int llo = lane & 15;

  __shared__ short se2[16 * 1024];    // e2(t) slice, swizzled (32KB)
  __shared__ short sh[16 * 1024];     // h(t)/h_new slice, swizzled (32KB)
  __shared__ float lds_g[6][16][17];  // raw gate accs: gi_r gi_z gi_n gh_r gh_z gh_n
  __shared__ float lds_p[5][16][17];  // phase-B partials [0..3] + savedA2 [4]
  __shared__ float lds_rs[16];        // 1/sum per row (e2 normalization)

  const int wbase = cg * (9 * 32 * 64) + lane;
  const int t0 = wave * 2, t1 = wave * 2 + 1;

  // ---- load step-invariant weights, then FORCE them resident ----
  bf16x8 wA0[32], wA1[32], wB8[8];
  #pragma unroll
  for (int ks = 0; ks < 32; ++ks) {
    wA0[ks] = packW[wbase + (t0 * 32 + ks) * 64];
    wA1[ks] = packW[wbase + (t1 * 32 + ks) * 64];
  }
  #pragma unroll
  for (int i = 0; i < 8; ++i) wB8[i] = packW[wbase + (8 * 32 + wave * 8 + i) * 64];
  #pragma unroll
  for (int ks = 0; ks < 32; ++ks) {
    asm volatile("" : "+v"(wA0[ks]));
    asm volatile("" : "+v"(wA1[ks]));
  }
  #pragma unroll
  for (int i = 0; i < 8; ++i) asm volatile("" : "+v"(wB8[i]));

  // ---- step-invariant per-thread scalars; h carried in-register ----
  const int row = tid >> 4, col = tid & 15;
  const int b_ = rg * 16 + row, j = cg * 16 + col;
  const float c_gr  = gictx[b_ * 3072 + j]        + b_hh[j];
  const float c_gz  = gictx[b_ * 3072 + 1024 + j] + b_hh[1024 + j];
  const float c_gn  = gictx[b_ * 3072 + 2048 + j];
  const float c_ghn = b_hh[2048 + j];
  const float c_oc  = ocbuf[b_ * HH + j];
  float h_reg = hidden[b_ * HH + j];
  const float c_bf  = bfv[cg * 16 + llo];

  // one flag per 128B line: flags[(rg*64 + cg) * 32]
  unsigned* myflags = flags + rg * (64 * 32);
  const short* e2slice = e2 + rg * 16384;
  short*       hslice  = hb + rg * 16384;

  // pre-stage h(0) into lds (phase-B stage keeps it current afterwards)
  STAGE_SLICE(sh, hslice);

  for (int t = 0; t <= LL; ++t) {
    // ---- stage e2(t); wave0 issues the rowsum-partials gather first ----
    unsigned long long pc[8];
    if (wave == 0 && t >= 1) {
      const float* pp = psumB + rg * 1024 + llo * 64 + lhi * 16;
      #pragma unroll
      for (int i = 0; i < 8; ++i) pc[i] = ld64c(pp + i * 2);
    }
    STAGE_SLICE(se2, e2slice);
    __syncthreads();   // sync1: stage visible

    // wave0: psumB reduce + lds_rs write AFTER sync1 (hidden under other
    // waves' phase-A MFMAs; readers need lds_rs only after sync2)
    if (wave == 0) {
      float total = 1.0f;
      if (t >= 1) {
        float s = 0.f;
        #pragma unroll
        for (int i = 0; i < 8; ++i) {
          union { unsigned long long u; float f[2]; } c; c.u = pc[i];
          s += c.f[0] + c.f[1];
        }
        s += __shfl_xor(s, 16);
        s += __shfl_xor(s, 32);
        total = s;
      }
      if (lane < 16) lds_rs[lane] = 1.0f / total;
    }

    // ================= PHASE A =================
    // waves: 0:{gi_r,gi_z}(A=e2) 1:{gi_n,Wo_d}(A=e2) 2:{gh_r,gh_z}(A=h) 3:{gh_n(A=h), Wf(A=e2)}
    const short* A0 = (wave < 2) ? se2 : sh;
    f32x4 acc0 = {0.f, 0.f, 0.f, 0.f}, acc1 = {0.f, 0.f, 0.f, 0.f};
    #pragma unroll
    for (int ks = 0; ks < 32; ++ks) {
      bf16x8 af0 = LFRAG(A0, ks);
      bf16x8 af1 = (wave == 3) ? LFRAG(se2, ks) : af0;
      acc0 = __builtin_amdgcn_mfma_f32_16x16x32_bf16(af0, wA0[ks], acc0, 0, 0, 0);
      acc1 = __builtin_amdgcn_mfma_f32_16x16x32_bf16(af1, wA1[ks], acc1, 0, 0, 0);
    }

    // stash raw accumulators to LDS
    f32x4 savedA2;
    if (wave == 0) {
      #pragma unroll
      for (int r = 0; r < 4; ++r) { lds_g[0][lhi*4+r][llo] = acc0[r]; lds_g[1][lhi*4+r][llo] = acc1[r]; }
    } else if (wave == 1) {
      #pragma unroll
      for (int r = 0; r < 4; ++r) { lds_g[2][lhi*4+r][llo] = acc0[r]; savedA2[r] = acc1[r]; }
    } else if (wave == 2) {
      #pragma unroll
      for (int r = 0; r < 4; ++r) { lds_g[3][lhi*4+r][llo] = acc0[r]; lds_g[4][lhi*4+r][llo] = acc1[r]; }
    } else {
      #pragma unroll
      for (int r = 0; r < 4; ++r) lds_g[5][lhi*4+r][llo] = acc0[r];
    }
    __syncthreads();   // sync2: lds_g + lds_rs visible

    // wave3: out logits -> eo, psumO partials (distinct slots, no atomics)
    f32x4 eo = {0.f, 0.f, 0.f, 0.f};
    if (wave == 3 && t >= 1) {
      #pragma unroll
      for (int r = 0; r < 4; ++r) eo[r] = __expf(acc1[r] * lds_rs[lhi*4+r] + c_bf);
      #pragma unroll
      for (int r = 0; r < 4; ++r) {
        float v_ = eo[r];
        v_ += __shfl_xor(v_, 1, 16); v_ += __shfl_xor(v_, 2, 16);
        v_ += __shfl_xor(v_, 4, 16); v_ += __shfl_xor(v_, 8, 16);
        if (llo == 0) stfc(psumO + rg * 1024 + (lhi*4+r) * 64 + cg, v_);
      }
    }

    // GRU elementwise: thread (row,col) owns h[b_,j]
    {
      float rsr = lds_rs[row];
      float gr  = lds_g[0][row][col] * rsr + lds_g[3][row][col] + c_gr;
      float gz  = lds_g[1][row][col] * rsr + lds_g[4][row][col] + c_gz;
      float gin = lds_g[2][row][col] * rsr + c_gn;
      float ghn = lds_g[5][row][col] + c_ghn;
      float rr = fsig(gr);
      float zz = fsig(gz);
      float nn = ftanh(gin + rr * ghn);
      float hnew = (1.0f - zz) * nn + zz * h_reg;
      h_reg = hnew;
      unsigned short hv = (unsigned short)f2bf(hnew);
      int other = __shfl_xor((int)hv, 1);
      if ((col & 1) == 0) {
        unsigned pk = (unsigned)hv | ((unsigned)(unsigned short)other << 16);
        st32c(hb + b_ * HH + (j & ~1), pk);
      }
    }

    // ---- bar1: h_new + psumO visible (flag barrier, rg-local) ----
    {
      unsigned ep = 2u * (unsigned)t + 1u;
      __syncthreads();                  // drains each wave's stores
      if (tid == 0) st32c(myflags + cg * 32, ep);
      if (wave == 0) {
        unsigned f;
        for (;;) {
          f = ld32c(myflags + lane * 32);
          if (!__any(f < ep)) break;
          __builtin_amdgcn_s_sleep(1);
        }
      }
      __syncthreads();
    }

    // ================= PHASE B =================
    if (t < LL) {
      STAGE_SLICE(sh, hslice);          // h(t+1) -> lds (also next phase A)
      __syncthreads();
      f32x4 accB = {0.f, 0.f, 0.f, 0.f};
      #pragma unroll
      for (int i = 0; i < 8; ++i) {
        int ks = wave * 8 + i;
        bf16x8 af = LFRAG(sh, ks);
        accB = __builtin_amdgcn_mfma_f32_16x16x32_bf16(af, wB8[i], accB, 0, 0, 0);
      }
      #pragma unroll
      for (int r = 0; r < 4; ++r) lds_p[wave][lhi*4+r][llo] = accB[r];
      if (wave == 1) {
        #pragma unroll
        for (int r = 0; r < 4; ++r) lds_p[4][lhi*4+r][llo] = savedA2[r];
      }
      __syncthreads();
      {
        float rsr = lds_rs[row];
        float l2 = lds_p[0][row][col] + lds_p[1][row][col] + lds_p[2][row][col] + lds_p[3][row][col]
                 + lds_p[4][row][col] * rsr + c_oc;
        float ev = __expf(l2);
        unsigned short eb = (unsigned short)f2bf(ev);
        int other = __shfl_xor((int)eb, 1);
        if ((col & 1) == 0) {
          unsigned pk = (unsigned)eb | ((unsigned)(unsigned short)other << 16);
          st32c(e2 + b_ * HH + (j & ~1), pk);
        }
        float sv = ev;
        sv += __shfl_xor(sv, 1, 16); sv += __shfl_xor(sv, 2, 16);
        sv += __shfl_xor(sv, 4, 16); sv += __shfl_xor(sv, 8, 16);
        if (col == 0) stfc(psumB + rg * 1024 + row * 64 + cg, sv);
      }

      // ---- bar2: e2 + psumB visible; out(t-1) hidden in the poll shadow ----
      {
        unsigned ep = 2u * (unsigned)t + 2u;
        __syncthreads();                 // drains e2 + psumB stores
        if (tid == 0) st32c(myflags + cg * 32, ep);
        // out(t-1): wave3 reduces psumO (posted+drained at bar1) and stores
        // the output row, overlapped with wave0's flag poll. Plain stores,
        // never re-read; drained by the closing __syncthreads.
        if (t >= 1 && wave == 3) {
          #pragma unroll
          for (int r = 0; r < 4; ++r) {
            int prow = lhi * 4 + r;
            const float* pp = psumO + rg * 1024 + prow * 64 + llo * 4;
            union { unsigned long long u; float f[2]; } c0, c1;
            c0.u = ld64c(pp); c1.u = ld64c(pp + 2);
            float s = c0.f[0] + c0.f[1] + c1.f[0] + c1.f[1];
            s += __shfl_xor(s, 1, 16); s += __shfl_xor(s, 2, 16);
            s += __shfl_xor(s, 4, 16); s += __shfl_xor(s, 8, 16);
            int b2 = rg * 16 + prow;
            outp[(size_t)(t - 1) * BB * VV + (size_t)b2 * VV + cg * 16 + llo] = eo[r] / s;
          }
        }
        if (wave == 0) {
          unsigned f;
          for (;;) {
            f = ld32c(myflags + lane * 32);
            if (!__any(f < ep)) break;
            __builtin_amdgcn_s_sleep(1);
          }
        }
        __syncthreads();
      }
    } else {
      // t == LL: no phase B / bar2 — emit final out(LL-1) directly
      if (wave == 3) {
        #pragma unroll
        for (int r = 0; r < 4; ++r) {
          int prow = lhi * 4 + r;
          const float* pp = psumO + rg * 1024 + prow * 64 + llo * 4;
          union { unsigned long long u; float f[2]; } c0, c1;
          c0.u = ld64c(pp); c1.u = ld64c(pp + 2);
          float s = c0.f[0] + c0.f[1] + c1.f[0] + c1.f[1];
          s += __shfl_xor(s, 1, 16); s += __shfl_xor(s, 2, 16);
          s += __shfl_xor(s, 4, 16); s += __shfl_xor(s, 8, 16);
          int b2 = rg * 16 + prow;
          outp[(size_t)(t - 1) * BB * VV + (size_t)b2 * VV + cg * 16 + llo] = eo[r] / s;
        }
      }
    }
  }
}

// ---------------- host launcher ----------------

extern "C" void kernel_launch(void* const* d_in, const int* in_sizes, int n_in,
                              void* d_out, int out_size, void* d_ws, size_t ws_size,
                              hipStream_t stream) {
  (void)in_sizes; (void)n_in; (void)out_size; (void)ws_size;
  const float* enc    = (const float*)d_in[0];
  const float* hidden = (const float*)d_in[1];
  const float* dec0   = (const float*)d_in[2];
  const float* Wa     = (const float*)d_in[3];
  // d_in[4] = ba: unused (softmax shift-invariance)
  const float* v      = (const float*)d_in[5];
  const float* W_ih   = (const float*)d_in[6];
  const float* b_ih   = (const float*)d_in[7];
  const float* W_hh   = (const float*)d_in[8];
  const float* b_hh   = (const float*)d_in[9];
  const float* Wo     = (const float*)d_in[10];
  const float* bo     = (const float*)d_in[11];
  const float* Wf     = (const float*)d_in[12];
  const float* bfv    = (const float*)d_in[13];

  char* ws = (char*)d_ws;
  float* ve    = (float*)(ws + OFF_VE);
  float* es    = (float*)(ws + OFF_ES);
  float* attn  = (float*)(ws + OFF_A);
  float* ctx   = (float*)(ws + OFF_CTX);
  float* gictx = (float*)(ws + OFF_GICTX);
  float* oc    = (float*)(ws + OFF_OC);
  unsigned* flags = (unsigned*)(ws + OFF_FLAGS);
  float* psumB = (float*)(ws + OFF_PSUMB);
  float* psumO = (float*)(ws + OFF_PSUMO);
  short* e2    = (short*)(ws + OFF_E2);
  short* hb    = (short*)(ws + OFF_HB0);
  short* packW = (short*)(ws + OFF_PACKW);

  hipLaunchKernelGGL(K_init, dim3(256), dim3(256), 0, stream, hidden, dec0, hb, e2, flags);
  hipLaunchKernelGGL(K_ve, dim3(16), dim3(64), 0, stream, Wa, v, ve);
  hipLaunchKernelGGL(K_escore, dim3(LL * BB), dim3(64), 0, stream, enc, ve, es);
  hipLaunchKernelGGL(K_asm, dim3(BB), dim3(256), 0, stream, es, attn);
  hipLaunchKernelGGL(K_ctx, dim3(512), dim3(128), 0, stream, enc, attn, ctx);
  hipLaunchKernelGGL(K_gictx, dim3(4096), dim3(64), 0, stream, ctx, W_ih, b_ih, Wo, bo, gictx, oc);
  hipLaunchKernelGGL(K_pack, dim3(64 * 9 * 32), dim3(64), 0, stream, W_ih, W_hh, Wo, Wf, packW);
  hipLaunchKernelGGL(K_step, dim3(256), dim3(256), 0, stream,
                     (const bf16x8*)packW, e2, hb, hidden, psumB, psumO,
                     gictx, oc, b_hh, bfv, (float*)d_out, flags);
}